// Round 11
// baseline (1157.161 us; speedup 1.0000x reference)
//
#include <hip/hip_runtime.h>
#include <cmath>

// ---------------------------------------------------------------------------
// Classifier pipeline, round 11: chain dispatch compaction (12 -> 10 launches).
// red1 fused into gG1, fixup fused into gG2 via deadlock-free last-block
// reduction (threadfence + per-panel atomic counter; reducer = 64th block).
//
// d_out byte layout (total 165,412,864 B):
//   feats [8192,1024] f32 @ 0
//   aug   [8192,1024] f32 @ 33,554,432
//   o1    [8192,1000] f32 @ 67,108,864
//   o2    [8192,1000] f32 @ 99,876,864
//   smx   [8192,1000] f32 @ 132,644,864
//
// Scratch (dead-region hosted; lifetime [first-write .. last-read]):
//   fh    fp16[8192*2048] @  67,108,864  [prep .. G1]        (o1 slot)
//   fetsh fp16[8192*1024] @  33,554,432  [G1 .. G2]          (aug slot)
//   P1    f32[8*1024*1024]@  33,554,432  [gG1 .. gG1-reduce] (ends 67,108,864)
//   P2    f32[8*1024*1000]@  33,554,432  [gG2 .. gG2-reduce] (ends 66,314,240)
//   sm1c  fp16[8192*512]  @  99,876,864  [masksm .. G3]      (o2 slot)
//   pidx  int[8192]       @ 108,265,472  [masksm .. G3]
//   pw    f32[8192]       @ 108,298,240  [masksm .. G3]
//   cthc  fp16[1024*512]  @ 116,654,080  [prep .. G3]
//   wbh   fp16[1024*2048] @ 118,751,232  [prep .. gG1]
//   wbl   fp16[1024*2048] @ 122,945,536  [prep .. gG1]
//   w2h   fp16[1024*1024] @ 132,644,864  [prep .. G4]        (smx slot)
//   w1h   fp16[1024*1024] @ 142,606,336  [prep .. gG2]
//   w1l   fp16[1024*1024] @ 144,703,488  [prep .. gG2]
//   fgh   fp16[1024*2048] @ 146,800,640  [masksm .. gG1]
//   fgl   fp16[1024*2048] @ 150,994,944  [masksm .. gG1]     (ends 155,189,248)
//   idx   int[1024]       @ 155,189,248  [masksm .. gG2]
//   cnt   int[17]         @ 155,193,344  [prep .. gG2]  (cnt, cnt1[8], cnt2[8])
//   fgsh  fp16[1024*1024] @ 155,197,440  [gG1 .. gG2]
//   fgsl  fp16[1024*1024] @ 157,294,592  [gG1 .. gG2]        (ends 159,391,744)
//   xh    fp16[8192*1024] @ 146,800,640  [rownorm .. G4]     (fg*/idx/fgs* dead)
// ---------------------------------------------------------------------------

typedef _Float16 h8 __attribute__((ext_vector_type(8)));
typedef _Float16 h4 __attribute__((ext_vector_type(4)));
typedef float f32x4 __attribute__((ext_vector_type(4)));

#define TAU 0.008f
#define CAP 1024

__device__ __forceinline__ void gload_lds16(const _Float16* g, _Float16* l) {
    __builtin_amdgcn_global_load_lds(
        (const __attribute__((address_space(1))) void*)g,
        (__attribute__((address_space(3))) void*)l, 16, 0, 0);
}

__device__ __forceinline__ void split4(f32x4 v, h4& h, h4& l) {
    #pragma unroll
    for (int j = 0; j < 4; ++j) {
        _Float16 hh = (_Float16)v[j];
        h[j] = hh;
        l[j] = (_Float16)((v[j] - (float)hh) * 2048.0f);
    }
}

// ===========================================================================
// prep: counters=0 + conv(features) + split(W_b) + padsplit(W1) + ctransc + W2
// sections: [0,4096) conv | [4096,5120) Wb | [5120,6144) W1
//           [6144,6656) ctransc | [6656,7680) W2
// ===========================================================================
__global__ __launch_bounds__(256) void prep_kernel(
    const float* __restrict__ features, _Float16* __restrict__ fh,
    const float* __restrict__ W_b, _Float16* __restrict__ wbh, _Float16* __restrict__ wbl,
    const float* __restrict__ W1, _Float16* __restrict__ w1h, _Float16* __restrict__ w1l,
    const float* __restrict__ W2, _Float16* __restrict__ w2h,
    const float* __restrict__ centroid, _Float16* __restrict__ cthc,
    int* __restrict__ cnt)
{
    __shared__ float tile[32][33];
    const int bid = blockIdx.x;
    const int t = threadIdx.x;
    if (bid == 0 && t < 17) cnt[t] = 0;      // cnt + cnt1[8] + cnt2[8]

    if (bid < 4096) {
        #pragma unroll
        for (int q = 0; q < 4; ++q) {
            const int i = (bid * 256 + t) + q * 4096 * 256;
            f32x4 v = ((const f32x4*)features)[i];
            h4 h;
            #pragma unroll
            for (int j = 0; j < 4; ++j) h[j] = (_Float16)v[j];
            ((h4*)fh)[i] = h;
        }
    } else if (bid < 5120) {
        const int i = (bid - 4096) * 512 + t;
        #pragma unroll
        for (int q = 0; q < 2; ++q) {
            const int k = i + q * 256;
            f32x4 v = ((const f32x4*)W_b)[k];
            h4 h, l; split4(v, h, l);
            ((h4*)wbh)[k] = h;
            ((h4*)wbl)[k] = l;
        }
    } else if (bid < 6144) {
        const int i = (bid - 5120) * 256 + t;
        const int r = i >> 8;
        f32x4 v = {0.f, 0.f, 0.f, 0.f};
        if (r < 1000) v = ((const f32x4*)W1)[i];
        h4 h, l; split4(v, h, l);
        ((h4*)w1h)[i] = h;
        ((h4*)w1l)[i] = l;
    } else if (bid < 6656) {
        // cthc[n][k] = k<500 ? centroid[500+k][n] : 0   (n:1024, k:512)
        const int local = bid - 6144;
        const int n0 = (local & 31) * 32, k0 = (local >> 5) * 32;
        const int tx = t & 31, ty = t >> 5;
        #pragma unroll
        for (int p = 0; p < 4; ++p) {
            int k = k0 + ty + p * 8;
            tile[ty + p * 8][tx] = (k < 500) ? centroid[(size_t)(500 + k) * 1024 + n0 + tx] : 0.0f;
        }
        __syncthreads();
        #pragma unroll
        for (int p = 0; p < 4; ++p) {
            int n = n0 + ty + p * 8;
            cthc[(size_t)n * 512 + k0 + tx] = (_Float16)tile[tx][ty + p * 8];
        }
    } else {
        const int i = (bid - 6656) * 256 + t;
        const int r = i >> 8;
        f32x4 v = {0.f, 0.f, 0.f, 0.f};
        if (r < 1000) v = ((const f32x4*)W2)[i];
        h4 h;
        #pragma unroll
        for (int j = 0; j < 4; ++j) h[j] = (_Float16)v[j];
        ((h4*)w2h)[i] = h;
    }
}

// ===========================================================================
// Main GEMM (m97 structure, fp16x1), 128x128 tile, 4 waves, gload_lds.
// MODE 1: C = A@B^T + bias(aux); also Ch = fp16(C)
// MODE 2: C = A@B^T, cols<nC
// MODE 3: C = A@B^T + aux[row,col] + pw[row]*cent[pidx[row]][col]
// MODE 4: C = A@B^T * 20, cols<nC
// ===========================================================================
template <int MODE>
__global__ __launch_bounds__(256, 4) void gemm16(
    const _Float16* __restrict__ Ah, int lda,
    const _Float16* __restrict__ Bh, int ldb, int K,
    float* __restrict__ C, int ldc, int nC,
    const float* __restrict__ aux, _Float16* __restrict__ Ch,
    const float* __restrict__ cent, const int* __restrict__ pidx,
    const float* __restrict__ pw)
{
    __shared__ _Float16 sAh[128 * 64];
    __shared__ _Float16 sBh[128 * 64];

    const int t = threadIdx.x;
    const int lane = t & 63, wid = t >> 6;
    // bijective XCD swizzle (512 wgs, 64/XCD -> 8 row-panels x 8 col)
    const int wg = blockIdx.x;
    const int wgid = (wg & 7) * 64 + (wg >> 3);
    const int row0 = (wgid >> 3) * 128, col0 = (wgid & 7) * 128;
    const int wr = wid >> 1, wc = wid & 1;
    const int fr = lane & 15;
    const int fk = (lane >> 4) * 8;
    const int srow = lane >> 3;
    const int scol = (lane & 7) * 8;

    f32x4 acc[4][4] = {};

    for (int k0 = 0; k0 < K; k0 += 64) {
        #pragma unroll
        for (int j = 0; j < 4; ++j) {
            int i = wid * 4 + j;
            int r = i * 8 + srow;
            gload_lds16(Ah + (size_t)(row0 + r) * lda + k0 + scol, &sAh[i * 512]);
            gload_lds16(Bh + (size_t)(col0 + r) * ldb + k0 + scol, &sBh[i * 512]);
        }
        __syncthreads();
        #pragma unroll
        for (int ks = 0; ks < 2; ++ks) {
            h8 ah[4];
            #pragma unroll
            for (int mf = 0; mf < 4; ++mf)
                ah[mf] = *(const h8*)&sAh[(wr * 64 + mf * 16 + fr) * 64 + ks * 32 + fk];
            #pragma unroll
            for (int nf = 0; nf < 4; ++nf) {
                h8 bh = *(const h8*)&sBh[(wc * 64 + nf * 16 + fr) * 64 + ks * 32 + fk];
                #pragma unroll
                for (int mf = 0; mf < 4; ++mf)
                    acc[mf][nf] = __builtin_amdgcn_mfma_f32_16x16x32_f16(ah[mf], bh, acc[mf][nf], 0, 0, 0);
            }
        }
        __syncthreads();
    }
    #pragma unroll
    for (int mf = 0; mf < 4; ++mf) {
        #pragma unroll
        for (int nf = 0; nf < 4; ++nf) {
            f32x4 v = acc[mf][nf];
            const int gcol = col0 + wc * 64 + nf * 16 + fr;
            const int rbase = row0 + wr * 64 + mf * 16 + (lane >> 4) * 4;
            #pragma unroll
            for (int j = 0; j < 4; ++j) {
                const int grow = rbase + j;
                float val = v[j];
                if constexpr (MODE == 1) val += aux[gcol];
                if constexpr (MODE == 3) {
                    const int p = pidx[grow];
                    val += aux[(size_t)grow * 1024 + gcol]
                         + pw[grow] * cent[(size_t)p * 1024 + gcol];
                }
                if constexpr (MODE == 4) val *= 20.0f;
                if (gcol < nC) {
                    C[(size_t)grow * ldc + gcol] = val;
                    if constexpr (MODE == 1)
                        Ch[(size_t)grow * 1024 + gcol] = (_Float16)val;
                }
            }
        }
    }
}

// shared device body: masked softmax on logits x (len 1000) -> COMPACT outputs:
// y[512] = sm1 over classes 500..999 (zeros if one-hot), pw/pidx rank-1 term.
__device__ __forceinline__ void masked_softmax_body(
    const float* __restrict__ x, _Float16* __restrict__ y,
    float* __restrict__ pwp, int* __restrict__ pidxp,
    int t, float* wv, int* wi, bool flag, int* d_idx, int* d_cnt, int rowid,
    int* s_slot)
{
    float bv = -1e30f, sv = -1e30f; int bi = 0;
    for (int c = t; c < 1000; c += 256) {
        float v = x[c];
        if (v > bv) { sv = bv; bv = v; bi = c; }
        else if (v > sv) sv = v;
    }
    #pragma unroll
    for (int off = 32; off > 0; off >>= 1) {
        float ov = __shfl_down(bv, off, 64);
        int   oi = __shfl_down(bi, off, 64);
        float os = __shfl_down(sv, off, 64);
        if (ov > bv || (ov == bv && oi < bi)) {
            sv = fmaxf(bv, os); bv = ov; bi = oi;
        } else {
            sv = fmaxf(sv, fmaxf(ov, os) == ov ? ov : os);
            sv = fmaxf(sv, ov); sv = fmaxf(sv, os);
        }
    }
    __shared__ float svv[4];
    const int lane = t & 63, wid = t >> 6;
    if (lane == 0) { wv[wid] = bv; wi[wid] = bi; svv[wid] = sv; }
    __syncthreads();
    __shared__ float s_m, s_tot; __shared__ int s_p;
    if (t == 0) {
        float mv = wv[0]; int mi = wi[0]; float m2 = svv[0];
        for (int w = 1; w < 4; ++w) {
            if (wv[w] > mv || (wv[w] == mv && wi[w] < mi)) {
                m2 = fmaxf(mv, svv[w]); mv = wv[w]; mi = wi[w];
            } else {
                m2 = fmaxf(m2, fmaxf(wv[w], svv[w]));
            }
        }
        s_p = mi; s_m = mv;
        int slot = -1;
        if (flag && (mv - m2) < TAU) {
            int q = atomicAdd(d_cnt, 1);
            if (q < CAP) { d_idx[q] = rowid; slot = q; }
        }
        *s_slot = slot;
    }
    __syncthreads();
    const int p = s_p; const float m = s_m;
    if (p >= 500) {
        for (int c = t; c < 512; c += 256) y[c] = (_Float16)0.0f;
        if (t == 0) { pwp[0] = 1.0f; pidxp[0] = p; }
    } else {
        float s = 0.f;
        for (int c = t; c < 1000; c += 256)
            if (c == p || c >= 500) s += expf(x[c] - m);
        #pragma unroll
        for (int off = 32; off > 0; off >>= 1) s += __shfl_down(s, off, 64);
        if (lane == 0) wv[wid] = s;
        __syncthreads();
        if (t == 0) s_tot = wv[0] + wv[1] + wv[2] + wv[3];
        __syncthreads();
        const float inv = 1.0f / s_tot;
        for (int c = t; c < 512; c += 256) {
            float v = 0.f;
            if (c < 500) v = expf(x[500 + c] - m) * inv;
            y[c] = (_Float16)v;
        }
        if (t == 0) { pwp[0] = inv; pidxp[0] = p; }  // sm1[p] = exp(0)*inv = inv
    }
}

// ===========================================================================
// Chain GEMM (m97, fp16x2, K-split partials via blockIdx.z, early-exit).
// CH==1: gG1 + fused red1 (last block of panel sums P1 + bias -> fgsh/fgsl)
// CH==2: gG2 + fused fixup (last block sums P2 -> masked-softmax rewrite)
// Deadlock-free: reducer is the 64th block to finish (threadfence+atomic);
// no block ever waits on another's progress.
// ===========================================================================
template <int CH>
__global__ __launch_bounds__(256, 2) void gemmc(
    const _Float16* __restrict__ Ah, const _Float16* __restrict__ Al, int lda,
    const _Float16* __restrict__ Bh, const _Float16* __restrict__ Bl, int ldb,
    int klen,
    float* __restrict__ C, int ldc, int nC,
    const int* __restrict__ cnt, int* __restrict__ pcnt,
    const float* __restrict__ bias,
    _Float16* __restrict__ fgsh, _Float16* __restrict__ fgsl,
    _Float16* __restrict__ sm1c, float* __restrict__ pwa, int* __restrict__ pidxa,
    const int* __restrict__ d_idx)
{
    __shared__ _Float16 sAh[128 * 64];
    __shared__ _Float16 sBh[128 * 64];
    __shared__ _Float16 sAl[128 * 64];
    __shared__ _Float16 sBl[128 * 64];
    __shared__ float xr[CH == 2 ? 1000 : 1];
    __shared__ float wvs[4]; __shared__ int wis[4];
    __shared__ int s_off; __shared__ int s_dummy;

    const int t = threadIdx.x;
    const int lane = t & 63, wid = t >> 6;
    const int row0 = blockIdx.y * 128, col0 = blockIdx.x * 128;
    const int kbase = blockIdx.z * klen;
    const int cntv = *cnt;
    if (row0 >= cntv) return;                 // inactive panel: no reduce needed
    const int wr = wid >> 1, wc = wid & 1;
    const int fr = lane & 15;
    const int fk = (lane >> 4) * 8;
    const int srow = lane >> 3;
    const int scol = (lane & 7) * 8;

    f32x4 acc[4][4] = {};
    f32x4 accc[4][4] = {};

    for (int k0 = kbase; k0 < kbase + klen; k0 += 64) {
        #pragma unroll
        for (int j = 0; j < 4; ++j) {
            int i = wid * 4 + j;
            int r = i * 8 + srow;
            const size_t ga = (size_t)(row0 + r) * lda + k0 + scol;
            const size_t gb = (size_t)(col0 + r) * ldb + k0 + scol;
            gload_lds16(Ah + ga, &sAh[i * 512]);
            gload_lds16(Bh + gb, &sBh[i * 512]);
            gload_lds16(Al + ga, &sAl[i * 512]);
            gload_lds16(Bl + gb, &sBl[i * 512]);
        }
        __syncthreads();
        #pragma unroll
        for (int ks = 0; ks < 2; ++ks) {
            h8 ah[4], al[4];
            #pragma unroll
            for (int mf = 0; mf < 4; ++mf) {
                int rr = wr * 64 + mf * 16 + fr;
                ah[mf] = *(const h8*)&sAh[rr * 64 + ks * 32 + fk];
                al[mf] = *(const h8*)&sAl[rr * 64 + ks * 32 + fk];
            }
            #pragma unroll
            for (int nf = 0; nf < 4; ++nf) {
                int cc = wc * 64 + nf * 16 + fr;
                h8 bh = *(const h8*)&sBh[cc * 64 + ks * 32 + fk];
                h8 bl = *(const h8*)&sBl[cc * 64 + ks * 32 + fk];
                #pragma unroll
                for (int mf = 0; mf < 4; ++mf) {
                    acc[mf][nf]  = __builtin_amdgcn_mfma_f32_16x16x32_f16(ah[mf], bh, acc[mf][nf], 0, 0, 0);
                    accc[mf][nf] = __builtin_amdgcn_mfma_f32_16x16x32_f16(ah[mf], bl, accc[mf][nf], 0, 0, 0);
                    accc[mf][nf] = __builtin_amdgcn_mfma_f32_16x16x32_f16(al[mf], bh, accc[mf][nf], 0, 0, 0);
                }
            }
        }
        __syncthreads();
    }
    float* Cz = C + (size_t)blockIdx.z * CAP * ldc;
    #pragma unroll
    for (int mf = 0; mf < 4; ++mf) {
        #pragma unroll
        for (int nf = 0; nf < 4; ++nf) {
            f32x4 v = acc[mf][nf] + accc[mf][nf] * (1.0f / 2048.0f);
            const int gcol = col0 + wc * 64 + nf * 16 + fr;
            const int rbase = row0 + wr * 64 + mf * 16 + (lane >> 4) * 4;
            #pragma unroll
            for (int j = 0; j < 4; ++j) {
                if (gcol < nC) Cz[(size_t)(rbase + j) * ldc + gcol] = v[j];
            }
        }
    }

    // ---- last-block reduction for this row-panel ----
    __threadfence();                          // make partial stores visible
    if (t == 0) s_off = atomicAdd(&pcnt[blockIdx.y], 1);
    __syncthreads();
    if (s_off != 63) return;
    __threadfence();                          // order subsequent loads

    if constexpr (CH == 1) {
        // red1: fgs = split( sum_z P1[z] + bias ) for this panel's 128 rows
        for (int e = t; e < 128 * 1024; e += 256) {
            const int rr = row0 + (e >> 10);
            const int c = e & 1023;
            const size_t o = (size_t)rr * 1024 + c;
            float s = bias[c];
            #pragma unroll
            for (int z = 0; z < 8; ++z) s += C[o + (size_t)z * CAP * 1024];
            _Float16 h = (_Float16)s;
            fgsh[o] = h;
            fgsl[o] = (_Float16)((s - (float)h) * 2048.0f);
        }
    } else {
        // fixup: sum P2 over z, then precise masked-softmax rewrite per slot
        const int send = (row0 + 128 < cntv) ? row0 + 128 : cntv;
        for (int slot = row0; slot < send; ++slot) {
            for (int c = t; c < 1000; c += 256) {
                const size_t o = (size_t)slot * 1000 + c;
                float s = 0.f;
                #pragma unroll
                for (int z = 0; z < 8; ++z) s += C[o + (size_t)z * CAP * 1000];
                xr[c] = s;
            }
            __syncthreads();
            const int row = d_idx[slot];
            masked_softmax_body(xr, sm1c + (size_t)row * 512, pwa + row, pidxa + row,
                                t, wvs, wis, false, nullptr, nullptr, 0, &s_dummy);
            __syncthreads();
        }
    }
}

// masked softmax + flagging + fused feature gather; LDS-cached logit row
__global__ __launch_bounds__(256) void masksm_kernel(
    const float* __restrict__ o1, _Float16* __restrict__ sm1c,
    float* __restrict__ pwa, int* __restrict__ pidxa,
    const float* __restrict__ features,
    _Float16* __restrict__ fgh, _Float16* __restrict__ fgl,
    int* __restrict__ d_idx, int* __restrict__ d_cnt)
{
    __shared__ float xs[1000];
    __shared__ float wv[4]; __shared__ int wi[4]; __shared__ int s_slot;
    const int row = blockIdx.x;
    const int t = threadIdx.x;
    const float* x = o1 + (size_t)row * 1000;
    for (int c = t; c < 1000; c += 256) xs[c] = x[c];
    __syncthreads();
    masked_softmax_body(xs, sm1c + (size_t)row * 512, pwa + row, pidxa + row,
                        t, wv, wi, true, d_idx, d_cnt, row, &s_slot);
    const int slot = s_slot;
    if (slot >= 0) {
        #pragma unroll
        for (int q = 0; q < 2; ++q) {
            int o = t * 8 + q * 4;
            f32x4 v = *(const f32x4*)(features + (size_t)row * 2048 + o);
            h4 h, l; split4(v, h, l);
            *(h4*)(fgh + (size_t)slot * 2048 + o) = h;
            *(h4*)(fgl + (size_t)slot * 2048 + o) = l;
        }
    }
}

// fused: invn = 1/max(||aug_row||,eps); xh = fp16(aug * invn)
__global__ __launch_bounds__(256) void rownorm_x_kernel(const float* __restrict__ aug,
                                                        _Float16* __restrict__ xh)
{
    const int row = blockIdx.x; const int t = threadIdx.x;
    f32x4 v = *((const f32x4*)(aug + (size_t)row * 1024) + t);
    float s = v[0]*v[0] + v[1]*v[1] + v[2]*v[2] + v[3]*v[3];
    #pragma unroll
    for (int off = 32; off > 0; off >>= 1) s += __shfl_down(s, off, 64);
    __shared__ float ws4[4]; __shared__ float s_inv;
    const int lane = t & 63, wid = t >> 6;
    if (lane == 0) ws4[wid] = s;
    __syncthreads();
    if (t == 0) {
        float tot = ws4[0] + ws4[1] + ws4[2] + ws4[3];
        s_inv = 1.0f / fmaxf(sqrtf(tot), 1e-12f);
    }
    __syncthreads();
    const float inv = s_inv;
    h4 h;
    #pragma unroll
    for (int j = 0; j < 4; ++j) h[j] = (_Float16)(v[j] * inv);
    *((h4*)(xh + (size_t)row * 1024) + t) = h;
}

// row softmax over 1000, register-resident (4 values/thread, 1 read, 1 expf)
__global__ __launch_bounds__(256) void softmax2_kernel(const float* __restrict__ o2,
                                                       float* __restrict__ out)
{
    const int row = blockIdx.x; const int t = threadIdx.x;
    const float* x = o2 + (size_t)row * 1000;
    float* y = out + (size_t)row * 1000;
    const bool has3 = (t < 232);
    float v0 = x[t], v1 = x[t + 256], v2 = x[t + 512];
    float v3 = has3 ? x[t + 768] : -1e30f;
    float m = fmaxf(fmaxf(v0, v1), fmaxf(v2, v3));
    #pragma unroll
    for (int off = 32; off > 0; off >>= 1) m = fmaxf(m, __shfl_down(m, off, 64));
    __shared__ float sm4[4]; __shared__ float s_m, s_s;
    const int lane = t & 63, wid = t >> 6;
    if (lane == 0) sm4[wid] = m;
    __syncthreads();
    if (t == 0) s_m = fmaxf(fmaxf(sm4[0], sm4[1]), fmaxf(sm4[2], sm4[3]));
    __syncthreads();
    m = s_m;
    float e0 = expf(v0 - m), e1 = expf(v1 - m), e2 = expf(v2 - m);
    float e3 = has3 ? expf(v3 - m) : 0.0f;
    float s = (e0 + e1) + (e2 + e3);
    #pragma unroll
    for (int off = 32; off > 0; off >>= 1) s += __shfl_down(s, off, 64);
    if (lane == 0) sm4[wid] = s;
    __syncthreads();
    if (t == 0) s_s = sm4[0] + sm4[1] + sm4[2] + sm4[3];
    __syncthreads();
    const float inv = 1.0f / s_s;
    y[t] = e0 * inv;
    y[t + 256] = e1 * inv;
    y[t + 512] = e2 * inv;
    if (has3) y[t + 768] = e3 * inv;
}

extern "C" void kernel_launch(void* const* d_in, const int* in_sizes, int n_in,
                              void* d_out, int out_size, void* d_ws, size_t ws_size,
                              hipStream_t stream)
{
    const float* features = (const float*)d_in[0];  // [8192,2048]
    const float* W_b      = (const float*)d_in[1];  // [1024,2048]
    const float* b_b      = (const float*)d_in[2];  // [1024]
    const float* W1       = (const float*)d_in[3];  // [1000,1024]
    const float* W2       = (const float*)d_in[4];  // [1000,1024]
    const float* centroid = (const float*)d_in[5];  // [1000,1024]

    char* base = (char*)d_out;
    float* feats = (float*)(base);
    float* aug   = (float*)(base + 33554432);
    float* o1    = (float*)(base + 67108864);
    float* o2    = (float*)(base + 99876864);
    float* smx   = (float*)(base + 132644864);

    _Float16* fh    = (_Float16*)(base + 67108864);
    _Float16* fetsh = (_Float16*)(base + 33554432);
    float*    P1    = (float*)   (base + 33554432);
    float*    P2    = (float*)   (base + 33554432);
    _Float16* sm1c  = (_Float16*)(base + 99876864);
    int*      pidx  = (int*)     (base + 108265472);
    float*    pw    = (float*)   (base + 108298240);
    _Float16* cthc  = (_Float16*)(base + 116654080);
    _Float16* wbh   = (_Float16*)(base + 118751232);
    _Float16* wbl   = (_Float16*)(base + 122945536);
    _Float16* w2h   = (_Float16*)(base + 132644864);
    _Float16* w1h   = (_Float16*)(base + 142606336);
    _Float16* w1l   = (_Float16*)(base + 144703488);
    _Float16* fgh   = (_Float16*)(base + 146800640);
    _Float16* fgl   = (_Float16*)(base + 150994944);
    int*      idx   = (int*)     (base + 155189248);
    int*      cnt   = (int*)     (base + 155193344);  // [0]=cnt, [1..8]=cnt1, [9..16]=cnt2
    _Float16* fgsh  = (_Float16*)(base + 155197440);
    _Float16* fgsl  = (_Float16*)(base + 157294592);
    _Float16* xh    = (_Float16*)(base + 146800640);

    // 1: all conversions + counters=0
    prep_kernel<<<7680, 256, 0, stream>>>(features, fh, W_b, wbh, wbl,
                                          W1, w1h, w1l, W2, w2h, centroid, cthc, cnt);
    // 2: G1 feats = F@W_b^T + b_b; epilogue also emits fetsh
    gemm16<1><<<512, 256, 0, stream>>>(fh, 2048, wbh, 2048, 2048,
                                       feats, 1024, 1024, b_b, fetsh,
                                       nullptr, nullptr, nullptr);
    // 3: G2 o1 = feats@W1^T
    gemm16<2><<<512, 256, 0, stream>>>(fetsh, 1024, w1h, 1024, 1024,
                                       o1, 1000, 1000, nullptr, nullptr,
                                       nullptr, nullptr, nullptr);
    // 4: masked softmax (compact) + flagging + fused gather
    masksm_kernel<<<8192, 256, 0, stream>>>(o1, sm1c, pw, pidx, features,
                                            fgh, fgl, idx, cnt);
    // 5: gG1 partials + fused red1 (last-block reduce)
    gemmc<1><<<dim3(8, CAP / 128, 8), 256, 0, stream>>>(
        fgh, fgl, 2048, wbh, wbl, 2048, 256, P1, 1024, 1024,
        cnt, cnt + 1, b_b, fgsh, fgsl, nullptr, nullptr, nullptr, nullptr);
    // 6: gG2 partials + fused fixup (last-block reduce + softmax rewrite)
    gemmc<2><<<dim3(8, CAP / 128, 8), 256, 0, stream>>>(
        fgsh, fgsl, 1024, w1h, w1l, 1024, 128, P2, 1000, 1000,
        cnt, cnt + 9, nullptr, nullptr, nullptr, sm1c, pw, pidx, idx);
    // 7: G3' aug = sm1c@cthc^T (K=512) + feats + pw*centroid[pidx]
    gemm16<3><<<512, 256, 0, stream>>>(sm1c, 512, cthc, 512, 512,
                                       aug, 1024, 1024, feats, nullptr,
                                       centroid, pidx, pw);
    // 8: rownorm + x conversion
    rownorm_x_kernel<<<8192, 256, 0, stream>>>(aug, xh);
    // 9: G4 o2 = x@W2^T * 20
    gemm16<4><<<512, 256, 0, stream>>>(xh, 1024, w2h, 1024, 1024,
                                       o2, 1000, 1000, nullptr, nullptr,
                                       nullptr, nullptr, nullptr);
    // 10: final softmax
    softmax2_kernel<<<8192, 256, 0, stream>>>(o2, smx);
}

// Round 12
// 255.260 us; speedup vs baseline: 4.5333x; 4.5333x over previous
//
#include <hip/hip_runtime.h>
#include <cmath>

// ---------------------------------------------------------------------------
// Classifier pipeline, round 12: REVERT to round-10 state (measured best,
// 258.2 us). Round 11's fused last-block fixup serialized 128 slots through
// one block (722 us dispatch) -- parallel launch width beats launch-gap
// savings for the fixup. This file is the round-10 kernel unchanged.
//
// d_out byte layout (total 165,412,864 B):
//   feats [8192,1024] f32 @ 0
//   aug   [8192,1024] f32 @ 33,554,432
//   o1    [8192,1000] f32 @ 67,108,864
//   o2    [8192,1000] f32 @ 99,876,864
//   smx   [8192,1000] f32 @ 132,644,864
//
// Scratch (dead-region hosted; lifetime [first-write .. last-read]):
//   fh    fp16[8192*2048] @  67,108,864  [prep .. G1]        (o1 slot)
//   fetsh fp16[8192*1024] @  33,554,432  [G1 .. G2]          (aug slot)
//   P1    f32[8*1024*1024]@  33,554,432  [gG1 .. red1]       (ends 67,108,864)
//   P2    f32[8*1024*1000]@  33,554,432  [gG2 .. fixup]      (ends 66,314,240)
//   sm1c  fp16[8192*512]  @  99,876,864  [masksm .. G3]      (o2 slot)
//   pidx  int[8192]       @ 108,265,472  [masksm .. G3]
//   pw    f32[8192]       @ 108,298,240  [masksm .. G3]
//   cthc  fp16[1024*512]  @ 116,654,080  [prep .. G3]
//   wbh   fp16[1024*2048] @ 118,751,232  [prep .. gG1]
//   wbl   fp16[1024*2048] @ 122,945,536  [prep .. gG1]
//   w2h   fp16[1024*1024] @ 132,644,864  [prep .. G4]        (smx slot)
//   w1h   fp16[1024*1024] @ 142,606,336  [prep .. gG2]
//   w1l   fp16[1024*1024] @ 144,703,488  [prep .. gG2]
//   fgh   fp16[1024*2048] @ 146,800,640  [masksm .. gG1]
//   fgl   fp16[1024*2048] @ 150,994,944  [masksm .. gG1]     (ends 155,189,248)
//   idx   int[1024]       @ 155,189,248  [masksm .. fixup]
//   cnt   int             @ 155,193,344  [prep .. fixup]
//   fgsh  fp16[1024*1024] @ 155,197,440  [red1 .. gG2]
//   fgsl  fp16[1024*1024] @ 157,294,592  [red1 .. gG2]       (ends 159,391,744)
//   xh    fp16[8192*1024] @ 146,800,640  [rownorm .. G4]     (fg*/idx/fgs* dead)
// ---------------------------------------------------------------------------

typedef _Float16 h8 __attribute__((ext_vector_type(8)));
typedef _Float16 h4 __attribute__((ext_vector_type(4)));
typedef float f32x4 __attribute__((ext_vector_type(4)));

#define TAU 0.008f
#define CAP 1024

__device__ __forceinline__ void gload_lds16(const _Float16* g, _Float16* l) {
    __builtin_amdgcn_global_load_lds(
        (const __attribute__((address_space(1))) void*)g,
        (__attribute__((address_space(3))) void*)l, 16, 0, 0);
}

__device__ __forceinline__ void split4(f32x4 v, h4& h, h4& l) {
    #pragma unroll
    for (int j = 0; j < 4; ++j) {
        _Float16 hh = (_Float16)v[j];
        h[j] = hh;
        l[j] = (_Float16)((v[j] - (float)hh) * 2048.0f);
    }
}

// ===========================================================================
// prep: cnt=0 + conv(features) + split(W_b) + padsplit(W1) + ctransc + pad(W2)
// sections: [0,4096) conv | [4096,5120) Wb | [5120,6144) W1
//           [6144,6656) ctransc | [6656,7680) W2
// ===========================================================================
__global__ __launch_bounds__(256) void prep_kernel(
    const float* __restrict__ features, _Float16* __restrict__ fh,
    const float* __restrict__ W_b, _Float16* __restrict__ wbh, _Float16* __restrict__ wbl,
    const float* __restrict__ W1, _Float16* __restrict__ w1h, _Float16* __restrict__ w1l,
    const float* __restrict__ W2, _Float16* __restrict__ w2h,
    const float* __restrict__ centroid, _Float16* __restrict__ cthc,
    int* __restrict__ cnt)
{
    __shared__ float tile[32][33];
    const int bid = blockIdx.x;
    const int t = threadIdx.x;
    if (bid == 0 && t == 0) *cnt = 0;

    if (bid < 4096) {
        #pragma unroll
        for (int q = 0; q < 4; ++q) {
            const int i = (bid * 256 + t) + q * 4096 * 256;
            f32x4 v = ((const f32x4*)features)[i];
            h4 h;
            #pragma unroll
            for (int j = 0; j < 4; ++j) h[j] = (_Float16)v[j];
            ((h4*)fh)[i] = h;
        }
    } else if (bid < 5120) {
        const int i = (bid - 4096) * 512 + t;
        #pragma unroll
        for (int q = 0; q < 2; ++q) {
            const int k = i + q * 256;
            f32x4 v = ((const f32x4*)W_b)[k];
            h4 h, l; split4(v, h, l);
            ((h4*)wbh)[k] = h;
            ((h4*)wbl)[k] = l;
        }
    } else if (bid < 6144) {
        const int i = (bid - 5120) * 256 + t;
        const int r = i >> 8;
        f32x4 v = {0.f, 0.f, 0.f, 0.f};
        if (r < 1000) v = ((const f32x4*)W1)[i];
        h4 h, l; split4(v, h, l);
        ((h4*)w1h)[i] = h;
        ((h4*)w1l)[i] = l;
    } else if (bid < 6656) {
        // cthc[n][k] = k<500 ? centroid[500+k][n] : 0   (n:1024, k:512)
        const int local = bid - 6144;
        const int n0 = (local & 31) * 32, k0 = (local >> 5) * 32;
        const int tx = t & 31, ty = t >> 5;
        #pragma unroll
        for (int p = 0; p < 4; ++p) {
            int k = k0 + ty + p * 8;
            tile[ty + p * 8][tx] = (k < 500) ? centroid[(size_t)(500 + k) * 1024 + n0 + tx] : 0.0f;
        }
        __syncthreads();
        #pragma unroll
        for (int p = 0; p < 4; ++p) {
            int n = n0 + ty + p * 8;
            cthc[(size_t)n * 512 + k0 + tx] = (_Float16)tile[tx][ty + p * 8];
        }
    } else {
        const int i = (bid - 6656) * 256 + t;
        const int r = i >> 8;
        f32x4 v = {0.f, 0.f, 0.f, 0.f};
        if (r < 1000) v = ((const f32x4*)W2)[i];
        h4 h;
        #pragma unroll
        for (int j = 0; j < 4; ++j) h[j] = (_Float16)v[j];
        ((h4*)w2h)[i] = h;
    }
}

// ===========================================================================
// Main GEMM (m97 structure, fp16x1), 128x128 tile, 4 waves, gload_lds.
// MODE 1: C = A@B^T + bias(aux); also Ch = fp16(C)
// MODE 2: C = A@B^T, cols<nC
// MODE 3: C = A@B^T + aux[row,col] + pw[row]*cent[pidx[row]][col]
// MODE 4: C = A@B^T * 20, cols<nC
// ===========================================================================
template <int MODE>
__global__ __launch_bounds__(256, 4) void gemm16(
    const _Float16* __restrict__ Ah, int lda,
    const _Float16* __restrict__ Bh, int ldb, int K,
    float* __restrict__ C, int ldc, int nC,
    const float* __restrict__ aux, _Float16* __restrict__ Ch,
    const float* __restrict__ cent, const int* __restrict__ pidx,
    const float* __restrict__ pw)
{
    __shared__ _Float16 sAh[128 * 64];
    __shared__ _Float16 sBh[128 * 64];

    const int t = threadIdx.x;
    const int lane = t & 63, wid = t >> 6;
    // bijective XCD swizzle (512 wgs, 64/XCD -> 8 row-panels x 8 col)
    const int wg = blockIdx.x;
    const int wgid = (wg & 7) * 64 + (wg >> 3);
    const int row0 = (wgid >> 3) * 128, col0 = (wgid & 7) * 128;
    const int wr = wid >> 1, wc = wid & 1;
    const int fr = lane & 15;
    const int fk = (lane >> 4) * 8;
    const int srow = lane >> 3;
    const int scol = (lane & 7) * 8;

    f32x4 acc[4][4] = {};

    for (int k0 = 0; k0 < K; k0 += 64) {
        #pragma unroll
        for (int j = 0; j < 4; ++j) {
            int i = wid * 4 + j;
            int r = i * 8 + srow;
            gload_lds16(Ah + (size_t)(row0 + r) * lda + k0 + scol, &sAh[i * 512]);
            gload_lds16(Bh + (size_t)(col0 + r) * ldb + k0 + scol, &sBh[i * 512]);
        }
        __syncthreads();
        #pragma unroll
        for (int ks = 0; ks < 2; ++ks) {
            h8 ah[4];
            #pragma unroll
            for (int mf = 0; mf < 4; ++mf)
                ah[mf] = *(const h8*)&sAh[(wr * 64 + mf * 16 + fr) * 64 + ks * 32 + fk];
            #pragma unroll
            for (int nf = 0; nf < 4; ++nf) {
                h8 bh = *(const h8*)&sBh[(wc * 64 + nf * 16 + fr) * 64 + ks * 32 + fk];
                #pragma unroll
                for (int mf = 0; mf < 4; ++mf)
                    acc[mf][nf] = __builtin_amdgcn_mfma_f32_16x16x32_f16(ah[mf], bh, acc[mf][nf], 0, 0, 0);
            }
        }
        __syncthreads();
    }
    #pragma unroll
    for (int mf = 0; mf < 4; ++mf) {
        #pragma unroll
        for (int nf = 0; nf < 4; ++nf) {
            f32x4 v = acc[mf][nf];
            const int gcol = col0 + wc * 64 + nf * 16 + fr;
            const int rbase = row0 + wr * 64 + mf * 16 + (lane >> 4) * 4;
            #pragma unroll
            for (int j = 0; j < 4; ++j) {
                const int grow = rbase + j;
                float val = v[j];
                if constexpr (MODE == 1) val += aux[gcol];
                if constexpr (MODE == 3) {
                    const int p = pidx[grow];
                    val += aux[(size_t)grow * 1024 + gcol]
                         + pw[grow] * cent[(size_t)p * 1024 + gcol];
                }
                if constexpr (MODE == 4) val *= 20.0f;
                if (gcol < nC) {
                    C[(size_t)grow * ldc + gcol] = val;
                    if constexpr (MODE == 1)
                        Ch[(size_t)grow * 1024 + gcol] = (_Float16)val;
                }
            }
        }
    }
}

// ===========================================================================
// Chain GEMM (m97, fp16x2, K-split partials via blockIdx.z, early-exit)
// ===========================================================================
__global__ __launch_bounds__(256, 2) void gemmc(
    const _Float16* __restrict__ Ah, const _Float16* __restrict__ Al, int lda,
    const _Float16* __restrict__ Bh, const _Float16* __restrict__ Bl, int ldb,
    int klen,
    float* __restrict__ C, int ldc, int nC,
    const int* __restrict__ cnt)
{
    __shared__ _Float16 sAh[128 * 64];
    __shared__ _Float16 sBh[128 * 64];
    __shared__ _Float16 sAl[128 * 64];
    __shared__ _Float16 sBl[128 * 64];

    const int t = threadIdx.x;
    const int lane = t & 63, wid = t >> 6;
    const int row0 = blockIdx.y * 128, col0 = blockIdx.x * 128;
    const int kbase = blockIdx.z * klen;
    if (row0 >= *cnt) return;
    const int wr = wid >> 1, wc = wid & 1;
    const int fr = lane & 15;
    const int fk = (lane >> 4) * 8;
    const int srow = lane >> 3;
    const int scol = (lane & 7) * 8;

    f32x4 acc[4][4] = {};
    f32x4 accc[4][4] = {};

    for (int k0 = kbase; k0 < kbase + klen; k0 += 64) {
        #pragma unroll
        for (int j = 0; j < 4; ++j) {
            int i = wid * 4 + j;
            int r = i * 8 + srow;
            const size_t ga = (size_t)(row0 + r) * lda + k0 + scol;
            const size_t gb = (size_t)(col0 + r) * ldb + k0 + scol;
            gload_lds16(Ah + ga, &sAh[i * 512]);
            gload_lds16(Bh + gb, &sBh[i * 512]);
            gload_lds16(Al + ga, &sAl[i * 512]);
            gload_lds16(Bl + gb, &sBl[i * 512]);
        }
        __syncthreads();
        #pragma unroll
        for (int ks = 0; ks < 2; ++ks) {
            h8 ah[4], al[4];
            #pragma unroll
            for (int mf = 0; mf < 4; ++mf) {
                int rr = wr * 64 + mf * 16 + fr;
                ah[mf] = *(const h8*)&sAh[rr * 64 + ks * 32 + fk];
                al[mf] = *(const h8*)&sAl[rr * 64 + ks * 32 + fk];
            }
            #pragma unroll
            for (int nf = 0; nf < 4; ++nf) {
                int cc = wc * 64 + nf * 16 + fr;
                h8 bh = *(const h8*)&sBh[cc * 64 + ks * 32 + fk];
                h8 bl = *(const h8*)&sBl[cc * 64 + ks * 32 + fk];
                #pragma unroll
                for (int mf = 0; mf < 4; ++mf) {
                    acc[mf][nf]  = __builtin_amdgcn_mfma_f32_16x16x32_f16(ah[mf], bh, acc[mf][nf], 0, 0, 0);
                    accc[mf][nf] = __builtin_amdgcn_mfma_f32_16x16x32_f16(ah[mf], bl, accc[mf][nf], 0, 0, 0);
                    accc[mf][nf] = __builtin_amdgcn_mfma_f32_16x16x32_f16(al[mf], bh, accc[mf][nf], 0, 0, 0);
                }
            }
        }
        __syncthreads();
    }
    float* Cz = C + (size_t)blockIdx.z * CAP * ldc;
    #pragma unroll
    for (int mf = 0; mf < 4; ++mf) {
        #pragma unroll
        for (int nf = 0; nf < 4; ++nf) {
            f32x4 v = acc[mf][nf] + accc[mf][nf] * (1.0f / 2048.0f);
            const int gcol = col0 + wc * 64 + nf * 16 + fr;
            const int rbase = row0 + wr * 64 + mf * 16 + (lane >> 4) * 4;
            #pragma unroll
            for (int j = 0; j < 4; ++j) {
                if (gcol < nC) Cz[(size_t)(rbase + j) * ldc + gcol] = v[j];
            }
        }
    }
}

// shared device body: masked softmax on logits x (len 1000) -> COMPACT outputs:
// y[512] = sm1 over classes 500..999 (zeros if one-hot), pw/pidx rank-1 term.
__device__ __forceinline__ void masked_softmax_body(
    const float* __restrict__ x, _Float16* __restrict__ y,
    float* __restrict__ pwp, int* __restrict__ pidxp,
    int t, float* wv, int* wi, bool flag, int* d_idx, int* d_cnt, int rowid,
    int* s_slot)
{
    float bv = -1e30f, sv = -1e30f; int bi = 0;
    for (int c = t; c < 1000; c += 256) {
        float v = x[c];
        if (v > bv) { sv = bv; bv = v; bi = c; }
        else if (v > sv) sv = v;
    }
    #pragma unroll
    for (int off = 32; off > 0; off >>= 1) {
        float ov = __shfl_down(bv, off, 64);
        int   oi = __shfl_down(bi, off, 64);
        float os = __shfl_down(sv, off, 64);
        if (ov > bv || (ov == bv && oi < bi)) {
            sv = fmaxf(bv, os); bv = ov; bi = oi;
        } else {
            sv = fmaxf(sv, fmaxf(ov, os) == ov ? ov : os);
            sv = fmaxf(sv, ov); sv = fmaxf(sv, os);
        }
    }
    __shared__ float svv[4];
    const int lane = t & 63, wid = t >> 6;
    if (lane == 0) { wv[wid] = bv; wi[wid] = bi; svv[wid] = sv; }
    __syncthreads();
    __shared__ float s_m, s_tot; __shared__ int s_p;
    if (t == 0) {
        float mv = wv[0]; int mi = wi[0]; float m2 = svv[0];
        for (int w = 1; w < 4; ++w) {
            if (wv[w] > mv || (wv[w] == mv && wi[w] < mi)) {
                m2 = fmaxf(mv, svv[w]); mv = wv[w]; mi = wi[w];
            } else {
                m2 = fmaxf(m2, fmaxf(wv[w], svv[w]));
            }
        }
        s_p = mi; s_m = mv;
        int slot = -1;
        if (flag && (mv - m2) < TAU) {
            int q = atomicAdd(d_cnt, 1);
            if (q < CAP) { d_idx[q] = rowid; slot = q; }
        }
        *s_slot = slot;
    }
    __syncthreads();
    const int p = s_p; const float m = s_m;
    if (p >= 500) {
        for (int c = t; c < 512; c += 256) y[c] = (_Float16)0.0f;
        if (t == 0) { pwp[0] = 1.0f; pidxp[0] = p; }
    } else {
        float s = 0.f;
        for (int c = t; c < 1000; c += 256)
            if (c == p || c >= 500) s += expf(x[c] - m);
        #pragma unroll
        for (int off = 32; off > 0; off >>= 1) s += __shfl_down(s, off, 64);
        if (lane == 0) wv[wid] = s;
        __syncthreads();
        if (t == 0) s_tot = wv[0] + wv[1] + wv[2] + wv[3];
        __syncthreads();
        const float inv = 1.0f / s_tot;
        for (int c = t; c < 512; c += 256) {
            float v = 0.f;
            if (c < 500) v = expf(x[500 + c] - m) * inv;
            y[c] = (_Float16)v;
        }
        if (t == 0) { pwp[0] = inv; pidxp[0] = p; }  // sm1[p] = exp(0)*inv = inv
    }
}

// masked softmax + flagging + fused feature gather; LDS-cached logit row
__global__ __launch_bounds__(256) void masksm_kernel(
    const float* __restrict__ o1, _Float16* __restrict__ sm1c,
    float* __restrict__ pwa, int* __restrict__ pidxa,
    const float* __restrict__ features,
    _Float16* __restrict__ fgh, _Float16* __restrict__ fgl,
    int* __restrict__ d_idx, int* __restrict__ d_cnt)
{
    __shared__ float xs[1000];
    __shared__ float wv[4]; __shared__ int wi[4]; __shared__ int s_slot;
    const int row = blockIdx.x;
    const int t = threadIdx.x;
    const float* x = o1 + (size_t)row * 1000;
    for (int c = t; c < 1000; c += 256) xs[c] = x[c];
    __syncthreads();
    masked_softmax_body(xs, sm1c + (size_t)row * 512, pwa + row, pidxa + row,
                        t, wv, wi, true, d_idx, d_cnt, row, &s_slot);
    const int slot = s_slot;
    if (slot >= 0) {
        #pragma unroll
        for (int q = 0; q < 2; ++q) {
            int o = t * 8 + q * 4;
            f32x4 v = *(const f32x4*)(features + (size_t)row * 2048 + o);
            h4 h, l; split4(v, h, l);
            *(h4*)(fgh + (size_t)slot * 2048 + o) = h;
            *(h4*)(fgl + (size_t)slot * 2048 + o) = l;
        }
    }
}

// fixup: sum 8 P2 partials, then precise masked-softmax rewrite (compact)
__global__ __launch_bounds__(256) void fixup_kernel(
    const float* __restrict__ P2, _Float16* __restrict__ sm1c,
    float* __restrict__ pwa, int* __restrict__ pidxa,
    const int* __restrict__ d_idx, const int* __restrict__ d_cnt)
{
    const int slot = blockIdx.x;
    if (slot >= *d_cnt || slot >= CAP) return;
    const int row = d_idx[slot];
    const int t = threadIdx.x;
    __shared__ float xr[1000];
    for (int c = t; c < 1000; c += 256) {
        const size_t o = (size_t)slot * 1000 + c;
        float s = 0.f;
        #pragma unroll
        for (int z = 0; z < 8; ++z) s += P2[o + (size_t)z * CAP * 1000];
        xr[c] = s;
    }
    __syncthreads();
    __shared__ float wv[4]; __shared__ int wi[4]; __shared__ int s_slot;
    masked_softmax_body(xr, sm1c + (size_t)row * 512, pwa + row, pidxa + row,
                        t, wv, wi, false, nullptr, nullptr, 0, &s_slot);
}

// red1: fgs = split( sum_z P1[z] + bias )
__global__ __launch_bounds__(256) void red1_kernel(const float* __restrict__ P1,
                                                   const float* __restrict__ bias,
                                                   _Float16* __restrict__ fgsh,
                                                   _Float16* __restrict__ fgsl,
                                                   const int* __restrict__ d_cnt)
{
    const int slot = blockIdx.x;
    if (slot >= *d_cnt || slot >= CAP) return;
    const int t = threadIdx.x;
    #pragma unroll
    for (int q = 0; q < 4; ++q) {
        const int c = t + q * 256;
        const size_t o = (size_t)slot * 1024 + c;
        float s = bias[c];
        #pragma unroll
        for (int z = 0; z < 8; ++z) s += P1[o + (size_t)z * CAP * 1024];
        _Float16 h = (_Float16)s;
        fgsh[o] = h;
        fgsl[o] = (_Float16)((s - (float)h) * 2048.0f);
    }
}

// fused: invn = 1/max(||aug_row||,eps); xh = fp16(aug * invn)
__global__ __launch_bounds__(256) void rownorm_x_kernel(const float* __restrict__ aug,
                                                        _Float16* __restrict__ xh)
{
    const int row = blockIdx.x; const int t = threadIdx.x;
    f32x4 v = *((const f32x4*)(aug + (size_t)row * 1024) + t);
    float s = v[0]*v[0] + v[1]*v[1] + v[2]*v[2] + v[3]*v[3];
    #pragma unroll
    for (int off = 32; off > 0; off >>= 1) s += __shfl_down(s, off, 64);
    __shared__ float ws4[4]; __shared__ float s_inv;
    const int lane = t & 63, wid = t >> 6;
    if (lane == 0) ws4[wid] = s;
    __syncthreads();
    if (t == 0) {
        float tot = ws4[0] + ws4[1] + ws4[2] + ws4[3];
        s_inv = 1.0f / fmaxf(sqrtf(tot), 1e-12f);
    }
    __syncthreads();
    const float inv = s_inv;
    h4 h;
    #pragma unroll
    for (int j = 0; j < 4; ++j) h[j] = (_Float16)(v[j] * inv);
    *((h4*)(xh + (size_t)row * 1024) + t) = h;
}

// row softmax over 1000, register-resident (4 values/thread, 1 read, 1 expf)
__global__ __launch_bounds__(256) void softmax2_kernel(const float* __restrict__ o2,
                                                       float* __restrict__ out)
{
    const int row = blockIdx.x; const int t = threadIdx.x;
    const float* x = o2 + (size_t)row * 1000;
    float* y = out + (size_t)row * 1000;
    const bool has3 = (t < 232);
    float v0 = x[t], v1 = x[t + 256], v2 = x[t + 512];
    float v3 = has3 ? x[t + 768] : -1e30f;
    float m = fmaxf(fmaxf(v0, v1), fmaxf(v2, v3));
    #pragma unroll
    for (int off = 32; off > 0; off >>= 1) m = fmaxf(m, __shfl_down(m, off, 64));
    __shared__ float sm4[4]; __shared__ float s_m, s_s;
    const int lane = t & 63, wid = t >> 6;
    if (lane == 0) sm4[wid] = m;
    __syncthreads();
    if (t == 0) s_m = fmaxf(fmaxf(sm4[0], sm4[1]), fmaxf(sm4[2], sm4[3]));
    __syncthreads();
    m = s_m;
    float e0 = expf(v0 - m), e1 = expf(v1 - m), e2 = expf(v2 - m);
    float e3 = has3 ? expf(v3 - m) : 0.0f;
    float s = (e0 + e1) + (e2 + e3);
    #pragma unroll
    for (int off = 32; off > 0; off >>= 1) s += __shfl_down(s, off, 64);
    if (lane == 0) sm4[wid] = s;
    __syncthreads();
    if (t == 0) s_s = sm4[0] + sm4[1] + sm4[2] + sm4[3];
    __syncthreads();
    const float inv = 1.0f / s_s;
    y[t] = e0 * inv;
    y[t + 256] = e1 * inv;
    y[t + 512] = e2 * inv;
    if (has3) y[t + 768] = e3 * inv;
}

extern "C" void kernel_launch(void* const* d_in, const int* in_sizes, int n_in,
                              void* d_out, int out_size, void* d_ws, size_t ws_size,
                              hipStream_t stream)
{
    const float* features = (const float*)d_in[0];  // [8192,2048]
    const float* W_b      = (const float*)d_in[1];  // [1024,2048]
    const float* b_b      = (const float*)d_in[2];  // [1024]
    const float* W1       = (const float*)d_in[3];  // [1000,1024]
    const float* W2       = (const float*)d_in[4];  // [1000,1024]
    const float* centroid = (const float*)d_in[5];  // [1000,1024]

    char* base = (char*)d_out;
    float* feats = (float*)(base);
    float* aug   = (float*)(base + 33554432);
    float* o1    = (float*)(base + 67108864);
    float* o2    = (float*)(base + 99876864);
    float* smx   = (float*)(base + 132644864);

    _Float16* fh    = (_Float16*)(base + 67108864);
    _Float16* fetsh = (_Float16*)(base + 33554432);
    float*    P1    = (float*)   (base + 33554432);
    float*    P2    = (float*)   (base + 33554432);
    _Float16* sm1c  = (_Float16*)(base + 99876864);
    int*      pidx  = (int*)     (base + 108265472);
    float*    pw    = (float*)   (base + 108298240);
    _Float16* cthc  = (_Float16*)(base + 116654080);
    _Float16* wbh   = (_Float16*)(base + 118751232);
    _Float16* wbl   = (_Float16*)(base + 122945536);
    _Float16* w2h   = (_Float16*)(base + 132644864);
    _Float16* w1h   = (_Float16*)(base + 142606336);
    _Float16* w1l   = (_Float16*)(base + 144703488);
    _Float16* fgh   = (_Float16*)(base + 146800640);
    _Float16* fgl   = (_Float16*)(base + 150994944);
    int*      idx   = (int*)     (base + 155189248);
    int*      cnt   = (int*)     (base + 155193344);
    _Float16* fgsh  = (_Float16*)(base + 155197440);
    _Float16* fgsl  = (_Float16*)(base + 157294592);
    _Float16* xh    = (_Float16*)(base + 146800640);

    // 1: all conversions + cnt=0
    prep_kernel<<<7680, 256, 0, stream>>>(features, fh, W_b, wbh, wbl,
                                          W1, w1h, w1l, W2, w2h, centroid, cthc, cnt);
    // 2: G1 feats = F@W_b^T + b_b; epilogue also emits fetsh
    gemm16<1><<<512, 256, 0, stream>>>(fh, 2048, wbh, 2048, 2048,
                                       feats, 1024, 1024, b_b, fetsh,
                                       nullptr, nullptr, nullptr);
    // 3: G2 o1 = feats@W1^T
    gemm16<2><<<512, 256, 0, stream>>>(fetsh, 1024, w1h, 1024, 1024,
                                       o1, 1000, 1000, nullptr, nullptr,
                                       nullptr, nullptr, nullptr);
    // 4: masked softmax (compact) + flagging + fused gather
    masksm_kernel<<<8192, 256, 0, stream>>>(o1, sm1c, pw, pidx, features,
                                            fgh, fgl, idx, cnt);
    // 5-8: correction chain (flagged rows only; blocks early-exit on cnt)
    gemmc<<<dim3(8, CAP / 128, 8), 256, 0, stream>>>(fgh, fgl, 2048, wbh, wbl, 2048, 256,
                                                     P1, 1024, 1024, cnt);
    red1_kernel<<<CAP, 256, 0, stream>>>(P1, b_b, fgsh, fgsl, cnt);
    gemmc<<<dim3(8, CAP / 128, 8), 256, 0, stream>>>(fgsh, fgsl, 1024, w1h, w1l, 1024, 128,
                                                     P2, 1000, 1000, cnt);
    fixup_kernel<<<CAP, 256, 0, stream>>>(P2, sm1c, pw, pidx, idx, cnt);
    // 9: G3' aug = sm1c@cthc^T (K=512) + feats + pw*centroid[pidx]
    gemm16<3><<<512, 256, 0, stream>>>(sm1c, 512, cthc, 512, 512,
                                       aug, 1024, 1024, feats, nullptr,
                                       centroid, pidx, pw);
    // 10: rownorm + x conversion
    rownorm_x_kernel<<<8192, 256, 0, stream>>>(aug, xh);
    // 11: G4 o2 = x@W2^T * 20
    gemm16<4><<<512, 256, 0, stream>>>(xh, 1024, w2h, 1024, 1024,
                                       o2, 1000, 1000, nullptr, nullptr,
                                       nullptr, nullptr, nullptr);
    // 12: final softmax
    softmax2_kernel<<<8192, 256, 0, stream>>>(o2, smx);
}